// Round 14
// baseline (37776.831 us; speedup 1.0000x reference)
//
#include <hip/hip_runtime.h>
#include <stdint.h>
#include <math.h>

// ---------------------------------------------------------------------------
// Batch-parallel fused graph-generator RNN (B=512, H=256, 50 steps, window 12)
// Round-14: r9 EXACT structure (best passing: 7408us) + wrap-&63 prefetch:
// r9's KGP=80 pad made the dist-8 prefetch read 8 garbage rows per matrix per
// pass (+12.5% L2 traffic, real vmcnt loads). Wrap eliminates it, and the
// tail prefetch (rows 0-7) pre-warms the NEXT scan step's first loads (same
// Ehh4 matrix). W4 footprint 3.93->3.14MB (L2-resident). Numerics VERBATIM.
// ---------------------------------------------------------------------------

#define NR 2
#define NWG 256
#define NTHR 512
#define MATS 49152u            // 64*768 float4s per matrix (no pad; wrap &63)

// ws layout (floats)
#define WS_W4   0u             // 4 * 196608 = 786432
#define WS_H0   786432u        // 131072
#define WS_EGI  917504u        // 256 * 13 * 1536 = 5111808
#define EGI_WG  19968u         // 13 * 1536 floats per WG

// output layout (floats)
#define O_NF 512u              // node feats [512][50][51]
#define O_EF 1306112u          // edge feats [522][512][9]
#define O_NL 3711488u          // node logprobs [512][50][3]
#define O_EL 3788288u          // edge logprobs [522][512][2]

// ---------------- threefry2x32 (exact JAX semantics) ----------------
__host__ __device__ inline void tf2x32(uint32_t k0, uint32_t k1,
                                       uint32_t x0, uint32_t x1,
                                       uint32_t& o0, uint32_t& o1) {
  uint32_t ks2 = k0 ^ k1 ^ 0x1BD11BDAu;
#define TFR(r) { x0 += x1; x1 = (x1 << r) | (x1 >> (32 - r)); x1 ^= x0; }
  x0 += k0; x1 += k1;
  TFR(13) TFR(15) TFR(26) TFR(6)
  x0 += k1; x1 += ks2 + 1u;
  TFR(17) TFR(29) TFR(16) TFR(24)
  x0 += ks2; x1 += k0 + 2u;
  TFR(13) TFR(15) TFR(26) TFR(6)
  x0 += k0; x1 += k1 + 3u;
  TFR(17) TFR(29) TFR(16) TFR(24)
  x0 += k1; x1 += ks2 + 4u;
  TFR(13) TFR(15) TFR(26) TFR(6)
  x0 += ks2; x1 += k0 + 5u;
#undef TFR
  o0 = x0; o1 = x1;
}

__device__ inline float gumbel_at(uint32_t k0, uint32_t k1, uint32_t idx) {
  uint32_t o0, o1;
  tf2x32(k0, k1, 0u, idx, o0, o1);
  uint32_t bits = o0 ^ o1;
  float u = __uint_as_float((bits >> 9) | 0x3f800000u) - 1.0f;
  u = fmaxf(u, 1.1754943508222875e-38f);
  return -logf(-logf(u));
}

__device__ __forceinline__ int ebase(int i) {
  return (i <= 12) ? i * (i - 1) / 2 : 78 + (i - 13) * 12;
}

// ---------------- setup kernel: W transpose + latproj ----------------
__global__ __launch_bounds__(256)
void setup_k(const float* __restrict__ nWih, const float* __restrict__ nWhh,
             const float* __restrict__ eWih, const float* __restrict__ eWhh,
             const float* __restrict__ z, const float* __restrict__ lpW,
             const float* __restrict__ lpb, float* __restrict__ ws) {
  const int wg = blockIdx.x, t = threadIdx.x;
  if (wg < 768) {
    int gid = wg * 256 + t;                 // 0..196607
    int mat = gid / 49152;
    int rem = gid - mat * 49152;
    int kg = rem / 768;
    int o = rem - kg * 768;
    const float* src = (mat == 0) ? nWih : (mat == 1) ? nWhh
                       : (mat == 2) ? eWih : eWhh;
    float4 v = *(const float4*)(src + (size_t)o * 256 + kg * 4);
    ((float4*)(ws + WS_W4))[(size_t)mat * MATS + (size_t)kg * 768 + o] = v;
  } else {
    float* h0 = ws + WS_H0;
    int idx = (wg - 768) * 256 + t;         // 0..16383
    const float alpha = 1.6732632423543772f, scale = 1.0507009873554805f;
    for (int q = 0; q < 8; ++q) {
      int flat = idx + q * 16384;           // 0..131071
      int m = flat >> 8, j = flat & 255;
      const float* zr = z + (size_t)m * 128;
      const float* wr = lpW + (size_t)j * 128;
      float s = 0.f;
      for (int k = 0; k < 128; ++k) s += zr[k] * wr[k];
      s += lpb[j];
      h0[(size_t)m * 256 + j] = scale * (s > 0.f ? s : alpha * expm1f(s));
    }
  }
}

// ---------------- coalesced 3-gate GEMV, W dist-8 pipeline (wrap) ----------
// a[g][r] = sum_k W[g*256+t][k] * x[r][k]; verbatim float4 dot order.
__device__ __forceinline__ void gemv3(const float4* __restrict__ Wq,
                                      const float (*__restrict__ x)[256],
                                      int t, float a[3][NR]) {
#pragma unroll
  for (int g = 0; g < 3; ++g)
#pragma unroll
    for (int r = 0; r < NR; ++r) a[g][r] = 0.f;
  float4 w0[8], w1[8], w2[8];
#pragma unroll
  for (int p = 0; p < 8; ++p) {
    const float4* bp = Wq + (size_t)p * 768;
    w0[p] = bp[t]; w1[p] = bp[256 + t]; w2[p] = bp[512 + t];
  }
  for (int kg = 0; kg < 64; kg += 8) {
#define G3BODY(p)                                                            \
    {                                                                        \
      float4 c0 = w0[p], c1 = w1[p], c2 = w2[p];                             \
      const float4* nx = Wq + (size_t)(((kg + (p) + 8) & 63)) * 768;         \
      w0[p] = nx[t]; w1[p] = nx[256 + t]; w2[p] = nx[512 + t];               \
      _Pragma("unroll")                                                      \
      for (int r = 0; r < NR; ++r) {                                         \
        const float4 xv = *(const float4*)&x[r][(kg + (p)) * 4];             \
        a[0][r] += xv.x * c0.x + xv.y * c0.y + xv.z * c0.z + xv.w * c0.w;    \
        a[1][r] += xv.x * c1.x + xv.y * c1.y + xv.z * c1.z + xv.w * c1.w;    \
        a[2][r] += xv.x * c2.x + xv.y * c2.y + xv.z * c2.z + xv.w * c2.w;    \
      }                                                                      \
    }
    G3BODY(0) G3BODY(1) G3BODY(2) G3BODY(3)
    G3BODY(4) G3BODY(5) G3BODY(6) G3BODY(7)
#undef G3BODY
  }
}

// ---------------- fused dual 3-gate GEMV, W dist-2 pipeline (wrap) ---------
__device__ __forceinline__ void gemv6(const float4* __restrict__ Wa,
                                      const float4* __restrict__ Wb,
                                      const float (*__restrict__ xa)[256],
                                      const float (*__restrict__ xh)[256],
                                      int t, float ga[3][NR], float gb[3][NR]) {
#pragma unroll
  for (int g = 0; g < 3; ++g)
#pragma unroll
    for (int r = 0; r < NR; ++r) { ga[g][r] = 0.f; gb[g][r] = 0.f; }
  float4 wa0[2], wa1[2], wa2[2], wb0[2], wb1[2], wb2[2];
#pragma unroll
  for (int p = 0; p < 2; ++p) {
    const float4* ba = Wa + (size_t)p * 768;
    const float4* bb = Wb + (size_t)p * 768;
    wa0[p] = ba[t]; wa1[p] = ba[256 + t]; wa2[p] = ba[512 + t];
    wb0[p] = bb[t]; wb1[p] = bb[256 + t]; wb2[p] = bb[512 + t];
  }
  for (int kg = 0; kg < 64; kg += 2) {
#define G6BODY(p)                                                            \
    {                                                                        \
      float4 cA0 = wa0[p], cA1 = wa1[p], cA2 = wa2[p];                       \
      float4 cB0 = wb0[p], cB1 = wb1[p], cB2 = wb2[p];                       \
      const float4* na = Wa + (size_t)(((kg + (p) + 2) & 63)) * 768;         \
      const float4* nb = Wb + (size_t)(((kg + (p) + 2) & 63)) * 768;         \
      wa0[p] = na[t]; wa1[p] = na[256 + t]; wa2[p] = na[512 + t];            \
      wb0[p] = nb[t]; wb1[p] = nb[256 + t]; wb2[p] = nb[512 + t];            \
      _Pragma("unroll")                                                      \
      for (int r = 0; r < NR; ++r) {                                         \
        const float4 xv = *(const float4*)&xa[r][(kg + (p)) * 4];            \
        const float4 hv = *(const float4*)&xh[r][(kg + (p)) * 4];            \
        ga[0][r] += xv.x * cA0.x + xv.y * cA0.y + xv.z * cA0.z + xv.w * cA0.w;\
        ga[1][r] += xv.x * cA1.x + xv.y * cA1.y + xv.z * cA1.z + xv.w * cA1.w;\
        ga[2][r] += xv.x * cA2.x + xv.y * cA2.y + xv.z * cA2.z + xv.w * cA2.w;\
        gb[0][r] += hv.x * cB0.x + hv.y * cB0.y + hv.z * cB0.z + hv.w * cB0.w;\
        gb[1][r] += hv.x * cB1.x + hv.y * cB1.y + hv.z * cB1.z + hv.w * cB1.w;\
        gb[2][r] += hv.x * cB2.x + hv.y * cB2.y + hv.z * cB2.z + hv.w * cB2.w;\
      }                                                                      \
    }
    G6BODY(0) G6BODY(1)
#undef G6BODY
  }
}

// ---------------- node classifier phase (verbatim math, nt stores) ---------
__device__ __forceinline__ void node_phase(
    float e0, float e1, float e2, float e3, int lane, int b, int step,
    const float* W, const float* bb, int nf, uint32_t kk0, uint32_t kk1,
    int coff, int jidx, bool do_arg, float* o_nf, float* o_nl, float* nnrow) {
  float ml = 0.f;
  for (int jf = 0; jf < nf; ++jf) {
    const float* wr = W + (size_t)jf * 256;
    float p = e0 * wr[lane] + e1 * wr[lane + 64] + e2 * wr[lane + 128] +
              e3 * wr[lane + 192];
#pragma unroll
    for (int d = 32; d; d >>= 1) p += __shfl_xor(p, d);
    if (lane == jf) ml = p + bb[jf];
  }
  const bool act = lane < nf;
  float g = act ? gumbel_at(kk0, kk1, (uint32_t)(b * nf + lane)) : 0.f;
  float tv = act ? (ml + g) / 1e-3f : -INFINITY;
  float mx = tv;
#pragma unroll
  for (int d = 32; d; d >>= 1) mx = fmaxf(mx, __shfl_xor(mx, d));
  float e = act ? expf(tv - mx) : 0.f;
  float se = e;
#pragma unroll
  for (int d = 32; d; d >>= 1) se += __shfl_xor(se, d);
  float s = act ? e / se : 0.f;
  float mx2 = act ? ml : -INFINITY;
#pragma unroll
  for (int d = 32; d; d >>= 1) mx2 = fmaxf(mx2, __shfl_xor(mx2, d));
  float e2v = act ? expf(ml - mx2) : 0.f;
  float se2 = e2v;
#pragma unroll
  for (int d = 32; d; d >>= 1) se2 += __shfl_xor(se2, d);
  float logp = ml - mx2 - logf(se2);
  float w = act ? s * logp : 0.f;
#pragma unroll
  for (int d = 32; d; d >>= 1) w += __shfl_xor(w, d);
  if (act)
    __builtin_nontemporal_store(s,
        &o_nf[((size_t)b * 50 + step) * 51 + coff + lane]);
  if (lane == 0)
    __builtin_nontemporal_store(w, &o_nl[((size_t)b * 50 + step) * 3 + jidx]);
  if (do_arg) {
    float av = act ? s : -1.f;
    int ai = lane;
#pragma unroll
    for (int d = 32; d; d >>= 1) {
      float ov = __shfl_xor(av, d);
      int oi = __shfl_xor(ai, d);
      if (ov > av || (ov == av && oi < ai)) { av = ov; ai = oi; }
    }
    if (lane == 0 && ai == 39 && nnrow[0] == -1.0f)
      nnrow[0] = (float)(step + 1);
  }
}

// ---------------- edge classifier phase (verbatim math, nt stores) ---------
__device__ __forceinline__ void edge_phase(
    float e0, float e1, float e2, float e3, int lane, int ridx, size_t orow,
    const float* W, const float* bb, int nf, uint32_t kk0, uint32_t kk1,
    int coff, int jidx, float* o_ef, float* o_el) {
  float ml = 0.f;
  for (int jf = 0; jf < nf; ++jf) {
    const float* wr = W + (size_t)jf * 256;
    float p = e0 * wr[lane] + e1 * wr[lane + 64] + e2 * wr[lane + 128] +
              e3 * wr[lane + 192];
#pragma unroll
    for (int d = 32; d; d >>= 1) p += __shfl_xor(p, d);
    if (lane == jf) ml = p + bb[jf];
  }
  const bool act = lane < nf;
  float g = act ? gumbel_at(kk0, kk1, (uint32_t)(ridx * nf + lane)) : 0.f;
  float tv = act ? (ml + g) / 1e-3f : -INFINITY;
  float mx = tv;
#pragma unroll
  for (int d = 32; d; d >>= 1) mx = fmaxf(mx, __shfl_xor(mx, d));
  float e = act ? expf(tv - mx) : 0.f;
  float se = e;
#pragma unroll
  for (int d = 32; d; d >>= 1) se += __shfl_xor(se, d);
  float s = act ? e / se : 0.f;
  // NOTE: edge path takes log_softmax of the SAMPLES (faithful to source)
  float mx2 = act ? s : -INFINITY;
#pragma unroll
  for (int d = 32; d; d >>= 1) mx2 = fmaxf(mx2, __shfl_xor(mx2, d));
  float e2v = act ? expf(s - mx2) : 0.f;
  float se2 = e2v;
#pragma unroll
  for (int d = 32; d; d >>= 1) se2 += __shfl_xor(se2, d);
  float logp = s - mx2 - logf(se2);
  float w = act ? s * logp : 0.f;
#pragma unroll
  for (int d = 32; d; d >>= 1) w += __shfl_xor(w, d);
  if (act) __builtin_nontemporal_store(s, &o_ef[orow * 9 + coff + lane]);
  if (lane == 0) __builtin_nontemporal_store(w, &o_el[orow * 2 + jidx]);
}

// ---------------- grouped classifier helpers (NR=2 wave mapping) -----------
__device__ __forceinline__ void node_cls_all(
    const float (*emb)[256], int tc, int b0, int step, const float* cW,
    const float* cB, float* o_nf, float* o_nl, float* nnL) {
  const int w = tc >> 6, lane = tc & 63;
  uint32_t k0_, k1_;
  if (w < 2) {
    const int row = w, b = b0 + row;
    const float e0 = emb[row][lane];
    const float e1 = emb[row][lane + 64];
    const float e2 = emb[row][lane + 128];
    const float e3 = emb[row][lane + 192];
    tf2x32(0u, 42u, 0u, (uint32_t)(step * 100 + 0), k0_, k1_);
    node_phase(e0, e1, e2, e3, lane, b, step, cW, cB, 40, k0_, k1_, 0, 0,
               true, o_nf, o_nl, &nnL[row]);
  } else {
    const int row = w - 2, b = b0 + row;
    const float e0 = emb[row][lane];
    const float e1 = emb[row][lane + 64];
    const float e2 = emb[row][lane + 128];
    const float e3 = emb[row][lane + 192];
    tf2x32(0u, 42u, 0u, (uint32_t)(step * 100 + 1), k0_, k1_);
    node_phase(e0, e1, e2, e3, lane, b, step, cW + 40 * 256, cB + 40, 6, k0_,
               k1_, 40, 1, false, o_nf, o_nl, &nnL[row]);
    tf2x32(0u, 42u, 0u, (uint32_t)(step * 100 + 2), k0_, k1_);
    node_phase(e0, e1, e2, e3, lane, b, step, cW + 46 * 256, cB + 46, 5, k0_,
               k1_, 46, 2, false, o_nf, o_nl, &nnL[row]);
  }
}

__device__ __forceinline__ void edge_cls_step(
    int i, int s, const float (*h2)[256], int tc, int b0, const float* cW,
    const float* cB, float* o_ef, float* o_el) {
  const int L = (i < 12) ? i : 12;
  const int tt = L - 1 - s;
  const int w = tc >> 6, lane = tc & 63;
  const int row = w & 1, b = b0 + row;
  const int ridx = tt * 512 + b;
  const size_t orow = (size_t)(ebase(i) + tt) * 512 + b;
  const float e0 = h2[row][lane];
  const float e1 = h2[row][lane + 64];
  const float e2 = h2[row][lane + 128];
  const float e3 = h2[row][lane + 192];
  uint32_t ka0, ka1;
  if (w < 2) {
    tf2x32(0u, 42u, 0u, (uint32_t)(i * 100 + 50), ka0, ka1);
    edge_phase(e0, e1, e2, e3, lane, ridx, orow, cW + 51 * 256, cB + 51, 5,
               ka0, ka1, 0, 0, o_ef, o_el);
  } else {
    tf2x32(0u, 42u, 0u, (uint32_t)(i * 100 + 51), ka0, ka1);
    edge_phase(e0, e1, e2, e3, lane, ridx, orow, cW + 56 * 256, cB + 56, 4,
               ka0, ka1, 5, 1, o_ef, o_el);
  }
}

__device__ __forceinline__ void do_eih(const float4* __restrict__ Eih4,
                                       const float (*__restrict__ x)[256],
                                       int tc, float* __restrict__ egi,
                                       int slot, float eb0, float eb1,
                                       float eb2) {
  float a[3][NR];
  gemv3(Eih4, x, tc, a);
  float* eg = egi + (size_t)slot * 1536 + tc * 6;
  float2 v0 = {a[0][0] + eb0, a[1][0] + eb1};
  float2 v1 = {a[2][0] + eb2, a[0][1] + eb0};
  float2 v2 = {a[1][1] + eb1, a[2][1] + eb2};
  *(float2*)(eg) = v0;
  *(float2*)(eg + 2) = v1;
  *(float2*)(eg + 4) = v2;
}

// ---------------- the fused kernel ----------------
__global__ __launch_bounds__(NTHR, 2)
void fused_rnn(const float* __restrict__ nbih, const float* __restrict__ nbhh,
               const float* __restrict__ ebih, const float* __restrict__ ebhh,
               const float* __restrict__ ncW0, const float* __restrict__ ncb0,
               const float* __restrict__ ncW1, const float* __restrict__ ncb1,
               const float* __restrict__ ncW2, const float* __restrict__ ncb2,
               const float* __restrict__ ecW0, const float* __restrict__ ecb0,
               const float* __restrict__ ecW1, const float* __restrict__ ecb1,
               float* __restrict__ ws, float* __restrict__ out) {
  __shared__ float xb[2][NR][256];   // node_emb ping-pong
  __shared__ float ht[NR][256];      // node hidden input
  __shared__ float hs[2][NR][256];   // edge_h ping-pong
  __shared__ float clsW[60][256];    // classifier weights
  __shared__ float clsB[64];         // classifier biases
  __shared__ float nnL[NR];

  const int t = threadIdx.x;
  const int wg = blockIdx.x;
  const int b0 = wg * NR;
  const bool isg = t < 256;          // waves 0-3: GEMV; waves 4-7: classifiers
  const int tc = t & 255;

  const float4* W4q = (const float4*)(ws + WS_W4);
  const float4* Wih4 = W4q;
  const float4* Whh4 = W4q + MATS;
  const float4* Eih4 = W4q + 2 * MATS;
  const float4* Ehh4 = W4q + 3 * MATS;
  const float* h0 = ws + WS_H0;
  float* egi = ws + WS_EGI + (size_t)wg * EGI_WG;

  float* o_nf = out + O_NF;
  float* o_ef = out + O_EF;
  float* o_nl = out + O_NL;
  float* o_el = out + O_EL;

  // ---- stage classifier weights/biases into LDS ----
  for (int x = t; x < 40 * 256; x += NTHR) (&clsW[0][0])[x] = ncW0[x];
  for (int x = t; x < 6 * 256; x += NTHR) (&clsW[40][0])[x] = ncW1[x];
  for (int x = t; x < 5 * 256; x += NTHR) (&clsW[46][0])[x] = ncW2[x];
  for (int x = t; x < 5 * 256; x += NTHR) (&clsW[51][0])[x] = ecW0[x];
  for (int x = t; x < 4 * 256; x += NTHR) (&clsW[56][0])[x] = ecW1[x];
  if (t < 40) clsB[t] = ncb0[t];
  else if (t < 46) clsB[t] = ncb1[t - 40];
  else if (t < 51) clsB[t] = ncb2[t - 46];
  else if (t < 56) clsB[t] = ecb0[t - 51];
  else if (t < 60) clsB[t] = ecb1[t - 56];

  const float nbih0 = nbih[tc], nbih1 = nbih[256 + tc], nbih2 = nbih[512 + tc];
  const float nbhh0 = nbhh[tc], nbhh1 = nbhh[256 + tc], nbhh2 = nbhh[512 + tc];
  const float ebih0 = ebih[tc], ebih1 = ebih[256 + tc], ebih2 = ebih[512 + tc];
  const float ebhh0 = ebhh[tc], ebhh1 = ebhh[256 + tc], ebhh2 = ebhh[512 + tc];

  if (isg) {
#pragma unroll
    for (int r = 0; r < NR; ++r) {
      hs[0][r][tc] = 0.f;
      ht[r][tc] = h0[(size_t)(b0 + r) * 256 + tc];
    }
  }
  if (t < NR) nnL[t] = -1.f;
  __syncthreads();

  int hp = 0;                        // hs[hp] holds current valid edge_h
  for (int i = 0; i < 50; ++i) {
    const int cur = i & 1, prv = cur ^ 1;
    const int L = (i < 12) ? i : 12;

    // ---- Phase A: build ht (gemv waves) ----
    if (i >= 1) {
      if (isg) {
#pragma unroll
        for (int r = 0; r < NR; ++r) {
          float v = xb[prv][r][tc];
          if (i >= 2) v += hs[hp][r][tc];
          ht[r][tc] = v;
        }
      }
      __syncthreads();
    }

    // ---- Phase B: node GRU (gemv) || deferred edge-cls(i-1, last) (cls) ----
    if (isg) {
      float gi[3][NR], gh[3][NR];
      if (i >= 1) {
        gemv6(Wih4, Whh4, xb[prv], ht, tc, gi, gh);
      } else {
        gemv3(Whh4, ht, tc, gh);
#pragma unroll
        for (int g = 0; g < 3; ++g)
#pragma unroll
          for (int r = 0; r < NR; ++r) gi[g][r] = 0.f;
      }
#pragma unroll
      for (int r = 0; r < NR; ++r) {
        float ir  = gi[0][r] + nbih0;
        float iz  = gi[1][r] + nbih1;
        float inn = gi[2][r] + nbih2;
        float hr = gh[0][r] + nbhh0;
        float hz = gh[1][r] + nbhh1;
        float hn = gh[2][r] + nbhh2;
        float h = ht[r][tc];
        float rr = 1.f / (1.f + expf(-(ir + hr)));
        float zg = 1.f / (1.f + expf(-(iz + hz)));
        float n = tanhf(inn + rr * hn);
        float hv = (1.f - zg) * n + zg * h;
        xb[cur][r][tc] = hv;
        if (i >= 1) hs[hp ^ 1][r][tc] = hs[hp][r][tc] + hv;  // edge_h += node_h
      }
    } else if (i >= 2) {
      const int Lp = ((i - 1) < 12) ? (i - 1) : 12;
      edge_cls_step(i - 1, Lp - 1, hs[hp], tc, b0, &clsW[0][0], clsB, o_ef,
                    o_el);
    }
    __syncthreads();
    if (i >= 1) hp ^= 1;

    // ---- Phase C: edge scan (gemv) || classifiers + eih (cls) ----
    if (i == 0) {
      if (isg) do_eih(Eih4, xb[cur], tc, egi, 0, ebih0, ebih1, ebih2);
      else node_cls_all(xb[cur], tc, b0, 0, &clsW[0][0], clsB, o_nf, o_nl,
                        nnL);
      __syncthreads();
    } else {
      const int sE = (L >= 2) ? 1 : 0;
      for (int s = 0; s < L; ++s) {
        if (isg) {
          const float* eg = egi + (size_t)((i - 1 - s) % 13) * 1536 + tc * 6;
          float2 f0 = *(const float2*)(eg);
          float2 f1 = *(const float2*)(eg + 2);
          float2 f2 = *(const float2*)(eg + 4);
          float a[3][NR];
          gemv3(Ehh4, hs[hp], tc, a);
          float ir_[NR] = {f0.x, f1.y};
          float iz_[NR] = {f0.y, f2.x};
          float in_[NR] = {f1.x, f2.y};
#pragma unroll
          for (int r = 0; r < NR; ++r) {
            float hr = a[0][r] + ebhh0;
            float hz = a[1][r] + ebhh1;
            float hn = a[2][r] + ebhh2;
            float h = hs[hp][r][tc];
            float rr = 1.f / (1.f + expf(-(ir_[r] + hr)));
            float zg = 1.f / (1.f + expf(-(iz_[r] + hz)));
            float n = tanhf(in_[r] + rr * hn);
            hs[hp ^ 1][r][tc] = (1.f - zg) * n + zg * h;
          }
        } else {
          if (s == 0)
            node_cls_all(xb[cur], tc, b0, i, &clsW[0][0], clsB, o_nf, o_nl,
                         nnL);
          if (s == sE && i <= 48)
            do_eih(Eih4, xb[cur], tc, egi, i % 13, ebih0, ebih1, ebih2);
          if (s >= 1)
            edge_cls_step(i, s - 1, hs[hp], tc, b0, &clsW[0][0], clsB, o_ef,
                          o_el);
        }
        __syncthreads();
        hp ^= 1;
      }
    }
  }

  // ---- final: last edge classifier + num_nodes ----
  if (!isg)
    edge_cls_step(49, 11, hs[hp], tc, b0, &clsW[0][0], clsB, o_ef, o_el);
  if (t < NR) {
    float v = nnL[t];
    __builtin_nontemporal_store((v == -1.f) ? 50.f : v, &out[b0 + t]);
  }
}

// ---------------- host ----------------
extern "C" void kernel_launch(void* const* d_in, const int* in_sizes, int n_in,
                              void* d_out, int out_size, void* d_ws,
                              size_t ws_size, hipStream_t stream) {
  (void)in_sizes; (void)n_in; (void)out_size; (void)ws_size;
  const float* z    = (const float*)d_in[0];
  const float* lpW  = (const float*)d_in[1];
  const float* lpb  = (const float*)d_in[2];
  const float* nWih = (const float*)d_in[3];
  const float* nWhh = (const float*)d_in[4];
  const float* nbih = (const float*)d_in[5];
  const float* nbhh = (const float*)d_in[6];
  const float* eWih = (const float*)d_in[7];
  const float* eWhh = (const float*)d_in[8];
  const float* ebih = (const float*)d_in[9];
  const float* ebhh = (const float*)d_in[10];
  const float* ncW0 = (const float*)d_in[11];
  const float* ncb0 = (const float*)d_in[12];
  const float* ncW1 = (const float*)d_in[13];
  const float* ncb1 = (const float*)d_in[14];
  const float* ncW2 = (const float*)d_in[15];
  const float* ncb2 = (const float*)d_in[16];
  const float* ecW0 = (const float*)d_in[17];
  const float* ecb0 = (const float*)d_in[18];
  const float* ecW1 = (const float*)d_in[19];
  const float* ecb1 = (const float*)d_in[20];

  setup_k<<<dim3(832), dim3(256), 0, stream>>>(nWih, nWhh, eWih, eWhh, z, lpW,
                                               lpb, (float*)d_ws);
  fused_rnn<<<dim3(NWG), dim3(NTHR), 0, stream>>>(
      nbih, nbhh, ebih, ebhh, ncW0, ncb0, ncW1, ncb1, ncW2, ncb2, ecW0, ecb0,
      ecW1, ecb1, (float*)d_ws, (float*)d_out);
}

// Round 15
// 7406.221 us; speedup vs baseline: 5.1007x; 5.1007x over previous
//
#include <hip/hip_runtime.h>
#include <stdint.h>
#include <math.h>

// ---------------------------------------------------------------------------
// Batch-parallel fused graph-generator RNN (B=512, H=256, 50 steps, window 12)
// Round-15: EXACT resubmission of round-9's kernel — the best passing config
// (7408us). Six structural variants (r10-r14) all regressed via (a) spill at
// the immovable 128-VGPR allocation or (b) added syncs from chain-splitting.
// 256 WG x NR=2, 8 waves (0-3 gemv / 4-7 classifiers), gemv3 dist-8 + gemv6
// dist-2 linear-address prefetch, KGP=80 pad, cached egi, NT output stores.
// Per-output arithmetic VERBATIM from all passing rounds => same numerics.
// ---------------------------------------------------------------------------

#define NR 2
#define NWG 256
#define NTHR 512
#define KGP 72                 // 64 kg rows + 8 pad (prefetch overrun)
#define MATS 55296u            // KGP*768 float4s per matrix

// ws layout (floats)
#define WS_W4   0u             // 4 * 221184 = 884736
#define WS_H0   884736u        // 131072
#define WS_EGI  1015808u       // 256 * 13 * 1536 = 5111808
#define EGI_WG  19968u         // 13 * 1536 floats per WG

// output layout (floats)
#define O_NF 512u              // node feats [512][50][51]
#define O_EF 1306112u          // edge feats [522][512][9]
#define O_NL 3711488u          // node logprobs [512][50][3]
#define O_EL 3788288u          // edge logprobs [522][512][2]

// ---------------- threefry2x32 (exact JAX semantics) ----------------
__host__ __device__ inline void tf2x32(uint32_t k0, uint32_t k1,
                                       uint32_t x0, uint32_t x1,
                                       uint32_t& o0, uint32_t& o1) {
  uint32_t ks2 = k0 ^ k1 ^ 0x1BD11BDAu;
#define TFR(r) { x0 += x1; x1 = (x1 << r) | (x1 >> (32 - r)); x1 ^= x0; }
  x0 += k0; x1 += k1;
  TFR(13) TFR(15) TFR(26) TFR(6)
  x0 += k1; x1 += ks2 + 1u;
  TFR(17) TFR(29) TFR(16) TFR(24)
  x0 += ks2; x1 += k0 + 2u;
  TFR(13) TFR(15) TFR(26) TFR(6)
  x0 += k0; x1 += k1 + 3u;
  TFR(17) TFR(29) TFR(16) TFR(24)
  x0 += k1; x1 += ks2 + 4u;
  TFR(13) TFR(15) TFR(26) TFR(6)
  x0 += ks2; x1 += k0 + 5u;
#undef TFR
  o0 = x0; o1 = x1;
}

__device__ inline float gumbel_at(uint32_t k0, uint32_t k1, uint32_t idx) {
  uint32_t o0, o1;
  tf2x32(k0, k1, 0u, idx, o0, o1);
  uint32_t bits = o0 ^ o1;
  float u = __uint_as_float((bits >> 9) | 0x3f800000u) - 1.0f;
  u = fmaxf(u, 1.1754943508222875e-38f);
  return -logf(-logf(u));
}

__device__ __forceinline__ int ebase(int i) {
  return (i <= 12) ? i * (i - 1) / 2 : 78 + (i - 13) * 12;
}

// ---------------- setup kernel: W transpose + latproj ----------------
__global__ __launch_bounds__(256)
void setup_k(const float* __restrict__ nWih, const float* __restrict__ nWhh,
             const float* __restrict__ eWih, const float* __restrict__ eWhh,
             const float* __restrict__ z, const float* __restrict__ lpW,
             const float* __restrict__ lpb, float* __restrict__ ws) {
  const int wg = blockIdx.x, t = threadIdx.x;
  if (wg < 768) {
    int gid = wg * 256 + t;                 // 0..196607
    int mat = gid / 49152;
    int rem = gid - mat * 49152;
    int kg = rem / 768;
    int o = rem - kg * 768;
    const float* src = (mat == 0) ? nWih : (mat == 1) ? nWhh
                       : (mat == 2) ? eWih : eWhh;
    float4 v = *(const float4*)(src + (size_t)o * 256 + kg * 4);
    ((float4*)(ws + WS_W4))[(size_t)mat * MATS + (size_t)kg * 768 + o] = v;
  } else {
    float* h0 = ws + WS_H0;
    int idx = (wg - 768) * 256 + t;         // 0..16383
    const float alpha = 1.6732632423543772f, scale = 1.0507009873554805f;
    for (int q = 0; q < 8; ++q) {
      int flat = idx + q * 16384;           // 0..131071
      int m = flat >> 8, j = flat & 255;
      const float* zr = z + (size_t)m * 128;
      const float* wr = lpW + (size_t)j * 128;
      float s = 0.f;
      for (int k = 0; k < 128; ++k) s += zr[k] * wr[k];
      s += lpb[j];
      h0[(size_t)m * 256 + j] = scale * (s > 0.f ? s : alpha * expm1f(s));
    }
  }
}

// ---------------- coalesced 3-gate GEMV, W dist-8 pipeline ----------------
// a[g][r] = sum_k W[g*256+t][k] * x[r][k]; verbatim float4 dot order.
__device__ __forceinline__ void gemv3(const float4* __restrict__ Wq,
                                      const float (*__restrict__ x)[256],
                                      int t, float a[3][NR]) {
#pragma unroll
  for (int g = 0; g < 3; ++g)
#pragma unroll
    for (int r = 0; r < NR; ++r) a[g][r] = 0.f;
  float4 w0[8], w1[8], w2[8];
#pragma unroll
  for (int p = 0; p < 8; ++p) {
    const float4* bp = Wq + (size_t)p * 768;
    w0[p] = bp[t]; w1[p] = bp[256 + t]; w2[p] = bp[512 + t];
  }
  for (int kg = 0; kg < 64; kg += 8) {
#define G3BODY(p)                                                            \
    {                                                                        \
      float4 c0 = w0[p], c1 = w1[p], c2 = w2[p];                             \
      const float4* nx = Wq + (size_t)(kg + (p) + 8) * 768;                  \
      w0[p] = nx[t]; w1[p] = nx[256 + t]; w2[p] = nx[512 + t];               \
      _Pragma("unroll")                                                      \
      for (int r = 0; r < NR; ++r) {                                         \
        const float4 xv = *(const float4*)&x[r][(kg + (p)) * 4];             \
        a[0][r] += xv.x * c0.x + xv.y * c0.y + xv.z * c0.z + xv.w * c0.w;    \
        a[1][r] += xv.x * c1.x + xv.y * c1.y + xv.z * c1.z + xv.w * c1.w;    \
        a[2][r] += xv.x * c2.x + xv.y * c2.y + xv.z * c2.z + xv.w * c2.w;    \
      }                                                                      \
    }
    G3BODY(0) G3BODY(1) G3BODY(2) G3BODY(3)
    G3BODY(4) G3BODY(5) G3BODY(6) G3BODY(7)
#undef G3BODY
  }
}

// ---------------- fused dual 3-gate GEMV, W dist-2 pipeline ----------------
__device__ __forceinline__ void gemv6(const float4* __restrict__ Wa,
                                      const float4* __restrict__ Wb,
                                      const float (*__restrict__ xa)[256],
                                      const float (*__restrict__ xh)[256],
                                      int t, float ga[3][NR], float gb[3][NR]) {
#pragma unroll
  for (int g = 0; g < 3; ++g)
#pragma unroll
    for (int r = 0; r < NR; ++r) { ga[g][r] = 0.f; gb[g][r] = 0.f; }
  float4 wa0[2], wa1[2], wa2[2], wb0[2], wb1[2], wb2[2];
#pragma unroll
  for (int p = 0; p < 2; ++p) {
    const float4* ba = Wa + (size_t)p * 768;
    const float4* bb = Wb + (size_t)p * 768;
    wa0[p] = ba[t]; wa1[p] = ba[256 + t]; wa2[p] = ba[512 + t];
    wb0[p] = bb[t]; wb1[p] = bb[256 + t]; wb2[p] = bb[512 + t];
  }
  for (int kg = 0; kg < 64; kg += 2) {
#define G6BODY(p)                                                            \
    {                                                                        \
      float4 cA0 = wa0[p], cA1 = wa1[p], cA2 = wa2[p];                       \
      float4 cB0 = wb0[p], cB1 = wb1[p], cB2 = wb2[p];                       \
      const float4* na = Wa + (size_t)(kg + (p) + 2) * 768;                  \
      const float4* nb = Wb + (size_t)(kg + (p) + 2) * 768;                  \
      wa0[p] = na[t]; wa1[p] = na[256 + t]; wa2[p] = na[512 + t];            \
      wb0[p] = nb[t]; wb1[p] = nb[256 + t]; wb2[p] = nb[512 + t];            \
      _Pragma("unroll")                                                      \
      for (int r = 0; r < NR; ++r) {                                         \
        const float4 xv = *(const float4*)&xa[r][(kg + (p)) * 4];            \
        const float4 hv = *(const float4*)&xh[r][(kg + (p)) * 4];            \
        ga[0][r] += xv.x * cA0.x + xv.y * cA0.y + xv.z * cA0.z + xv.w * cA0.w;\
        ga[1][r] += xv.x * cA1.x + xv.y * cA1.y + xv.z * cA1.z + xv.w * cA1.w;\
        ga[2][r] += xv.x * cA2.x + xv.y * cA2.y + xv.z * cA2.z + xv.w * cA2.w;\
        gb[0][r] += hv.x * cB0.x + hv.y * cB0.y + hv.z * cB0.z + hv.w * cB0.w;\
        gb[1][r] += hv.x * cB1.x + hv.y * cB1.y + hv.z * cB1.z + hv.w * cB1.w;\
        gb[2][r] += hv.x * cB2.x + hv.y * cB2.y + hv.z * cB2.z + hv.w * cB2.w;\
      }                                                                      \
    }
    G6BODY(0) G6BODY(1)
#undef G6BODY
  }
}

// ---------------- node classifier phase (verbatim math, nt stores) ---------
__device__ __forceinline__ void node_phase(
    float e0, float e1, float e2, float e3, int lane, int b, int step,
    const float* W, const float* bb, int nf, uint32_t kk0, uint32_t kk1,
    int coff, int jidx, bool do_arg, float* o_nf, float* o_nl, float* nnrow) {
  float ml = 0.f;
  for (int jf = 0; jf < nf; ++jf) {
    const float* wr = W + (size_t)jf * 256;
    float p = e0 * wr[lane] + e1 * wr[lane + 64] + e2 * wr[lane + 128] +
              e3 * wr[lane + 192];
#pragma unroll
    for (int d = 32; d; d >>= 1) p += __shfl_xor(p, d);
    if (lane == jf) ml = p + bb[jf];
  }
  const bool act = lane < nf;
  float g = act ? gumbel_at(kk0, kk1, (uint32_t)(b * nf + lane)) : 0.f;
  float tv = act ? (ml + g) / 1e-3f : -INFINITY;
  float mx = tv;
#pragma unroll
  for (int d = 32; d; d >>= 1) mx = fmaxf(mx, __shfl_xor(mx, d));
  float e = act ? expf(tv - mx) : 0.f;
  float se = e;
#pragma unroll
  for (int d = 32; d; d >>= 1) se += __shfl_xor(se, d);
  float s = act ? e / se : 0.f;
  float mx2 = act ? ml : -INFINITY;
#pragma unroll
  for (int d = 32; d; d >>= 1) mx2 = fmaxf(mx2, __shfl_xor(mx2, d));
  float e2v = act ? expf(ml - mx2) : 0.f;
  float se2 = e2v;
#pragma unroll
  for (int d = 32; d; d >>= 1) se2 += __shfl_xor(se2, d);
  float logp = ml - mx2 - logf(se2);
  float w = act ? s * logp : 0.f;
#pragma unroll
  for (int d = 32; d; d >>= 1) w += __shfl_xor(w, d);
  if (act)
    __builtin_nontemporal_store(s,
        &o_nf[((size_t)b * 50 + step) * 51 + coff + lane]);
  if (lane == 0)
    __builtin_nontemporal_store(w, &o_nl[((size_t)b * 50 + step) * 3 + jidx]);
  if (do_arg) {
    float av = act ? s : -1.f;
    int ai = lane;
#pragma unroll
    for (int d = 32; d; d >>= 1) {
      float ov = __shfl_xor(av, d);
      int oi = __shfl_xor(ai, d);
      if (ov > av || (ov == av && oi < ai)) { av = ov; ai = oi; }
    }
    if (lane == 0 && ai == 39 && nnrow[0] == -1.0f)
      nnrow[0] = (float)(step + 1);
  }
}

// ---------------- edge classifier phase (verbatim math, nt stores) ---------
__device__ __forceinline__ void edge_phase(
    float e0, float e1, float e2, float e3, int lane, int ridx, size_t orow,
    const float* W, const float* bb, int nf, uint32_t kk0, uint32_t kk1,
    int coff, int jidx, float* o_ef, float* o_el) {
  float ml = 0.f;
  for (int jf = 0; jf < nf; ++jf) {
    const float* wr = W + (size_t)jf * 256;
    float p = e0 * wr[lane] + e1 * wr[lane + 64] + e2 * wr[lane + 128] +
              e3 * wr[lane + 192];
#pragma unroll
    for (int d = 32; d; d >>= 1) p += __shfl_xor(p, d);
    if (lane == jf) ml = p + bb[jf];
  }
  const bool act = lane < nf;
  float g = act ? gumbel_at(kk0, kk1, (uint32_t)(ridx * nf + lane)) : 0.f;
  float tv = act ? (ml + g) / 1e-3f : -INFINITY;
  float mx = tv;
#pragma unroll
  for (int d = 32; d; d >>= 1) mx = fmaxf(mx, __shfl_xor(mx, d));
  float e = act ? expf(tv - mx) : 0.f;
  float se = e;
#pragma unroll
  for (int d = 32; d; d >>= 1) se += __shfl_xor(se, d);
  float s = act ? e / se : 0.f;
  // NOTE: edge path takes log_softmax of the SAMPLES (faithful to source)
  float mx2 = act ? s : -INFINITY;
#pragma unroll
  for (int d = 32; d; d >>= 1) mx2 = fmaxf(mx2, __shfl_xor(mx2, d));
  float e2v = act ? expf(s - mx2) : 0.f;
  float se2 = e2v;
#pragma unroll
  for (int d = 32; d; d >>= 1) se2 += __shfl_xor(se2, d);
  float logp = s - mx2 - logf(se2);
  float w = act ? s * logp : 0.f;
#pragma unroll
  for (int d = 32; d; d >>= 1) w += __shfl_xor(w, d);
  if (act) __builtin_nontemporal_store(s, &o_ef[orow * 9 + coff + lane]);
  if (lane == 0) __builtin_nontemporal_store(w, &o_el[orow * 2 + jidx]);
}

// ---------------- grouped classifier helpers (NR=2 wave mapping) -----------
__device__ __forceinline__ void node_cls_all(
    const float (*emb)[256], int tc, int b0, int step, const float* cW,
    const float* cB, float* o_nf, float* o_nl, float* nnL) {
  const int w = tc >> 6, lane = tc & 63;
  uint32_t k0_, k1_;
  if (w < 2) {
    const int row = w, b = b0 + row;
    const float e0 = emb[row][lane];
    const float e1 = emb[row][lane + 64];
    const float e2 = emb[row][lane + 128];
    const float e3 = emb[row][lane + 192];
    tf2x32(0u, 42u, 0u, (uint32_t)(step * 100 + 0), k0_, k1_);
    node_phase(e0, e1, e2, e3, lane, b, step, cW, cB, 40, k0_, k1_, 0, 0,
               true, o_nf, o_nl, &nnL[row]);
  } else {
    const int row = w - 2, b = b0 + row;
    const float e0 = emb[row][lane];
    const float e1 = emb[row][lane + 64];
    const float e2 = emb[row][lane + 128];
    const float e3 = emb[row][lane + 192];
    tf2x32(0u, 42u, 0u, (uint32_t)(step * 100 + 1), k0_, k1_);
    node_phase(e0, e1, e2, e3, lane, b, step, cW + 40 * 256, cB + 40, 6, k0_,
               k1_, 40, 1, false, o_nf, o_nl, &nnL[row]);
    tf2x32(0u, 42u, 0u, (uint32_t)(step * 100 + 2), k0_, k1_);
    node_phase(e0, e1, e2, e3, lane, b, step, cW + 46 * 256, cB + 46, 5, k0_,
               k1_, 46, 2, false, o_nf, o_nl, &nnL[row]);
  }
}

__device__ __forceinline__ void edge_cls_step(
    int i, int s, const float (*h2)[256], int tc, int b0, const float* cW,
    const float* cB, float* o_ef, float* o_el) {
  const int L = (i < 12) ? i : 12;
  const int tt = L - 1 - s;
  const int w = tc >> 6, lane = tc & 63;
  const int row = w & 1, b = b0 + row;
  const int ridx = tt * 512 + b;
  const size_t orow = (size_t)(ebase(i) + tt) * 512 + b;
  const float e0 = h2[row][lane];
  const float e1 = h2[row][lane + 64];
  const float e2 = h2[row][lane + 128];
  const float e3 = h2[row][lane + 192];
  uint32_t ka0, ka1;
  if (w < 2) {
    tf2x32(0u, 42u, 0u, (uint32_t)(i * 100 + 50), ka0, ka1);
    edge_phase(e0, e1, e2, e3, lane, ridx, orow, cW + 51 * 256, cB + 51, 5,
               ka0, ka1, 0, 0, o_ef, o_el);
  } else {
    tf2x32(0u, 42u, 0u, (uint32_t)(i * 100 + 51), ka0, ka1);
    edge_phase(e0, e1, e2, e3, lane, ridx, orow, cW + 56 * 256, cB + 56, 4,
               ka0, ka1, 5, 1, o_ef, o_el);
  }
}

__device__ __forceinline__ void do_eih(const float4* __restrict__ Eih4,
                                       const float (*__restrict__ x)[256],
                                       int tc, float* __restrict__ egi,
                                       int slot, float eb0, float eb1,
                                       float eb2) {
  float a[3][NR];
  gemv3(Eih4, x, tc, a);
  float* eg = egi + (size_t)slot * 1536 + tc * 6;
  float2 v0 = {a[0][0] + eb0, a[1][0] + eb1};
  float2 v1 = {a[2][0] + eb2, a[0][1] + eb0};
  float2 v2 = {a[1][1] + eb1, a[2][1] + eb2};
  *(float2*)(eg) = v0;
  *(float2*)(eg + 2) = v1;
  *(float2*)(eg + 4) = v2;
}

// ---------------- the fused kernel ----------------
__global__ __launch_bounds__(NTHR, 2)
void fused_rnn(const float* __restrict__ nbih, const float* __restrict__ nbhh,
               const float* __restrict__ ebih, const float* __restrict__ ebhh,
               const float* __restrict__ ncW0, const float* __restrict__ ncb0,
               const float* __restrict__ ncW1, const float* __restrict__ ncb1,
               const float* __restrict__ ncW2, const float* __restrict__ ncb2,
               const float* __restrict__ ecW0, const float* __restrict__ ecb0,
               const float* __restrict__ ecW1, const float* __restrict__ ecb1,
               float* __restrict__ ws, float* __restrict__ out) {
  __shared__ float xb[2][NR][256];   // node_emb ping-pong
  __shared__ float ht[NR][256];      // node hidden input
  __shared__ float hs[2][NR][256];   // edge_h ping-pong
  __shared__ float clsW[60][256];    // classifier weights
  __shared__ float clsB[64];         // classifier biases
  __shared__ float nnL[NR];

  const int t = threadIdx.x;
  const int wg = blockIdx.x;
  const int b0 = wg * NR;
  const bool isg = t < 256;          // waves 0-3: GEMV; waves 4-7: classifiers
  const int tc = t & 255;

  const float4* W4q = (const float4*)(ws + WS_W4);
  const float4* Wih4 = W4q;
  const float4* Whh4 = W4q + MATS;
  const float4* Eih4 = W4q + 2 * MATS;
  const float4* Ehh4 = W4q + 3 * MATS;
  const float* h0 = ws + WS_H0;
  float* egi = ws + WS_EGI + (size_t)wg * EGI_WG;

  float* o_nf = out + O_NF;
  float* o_ef = out + O_EF;
  float* o_nl = out + O_NL;
  float* o_el = out + O_EL;

  // ---- stage classifier weights/biases into LDS ----
  for (int x = t; x < 40 * 256; x += NTHR) (&clsW[0][0])[x] = ncW0[x];
  for (int x = t; x < 6 * 256; x += NTHR) (&clsW[40][0])[x] = ncW1[x];
  for (int x = t; x < 5 * 256; x += NTHR) (&clsW[46][0])[x] = ncW2[x];
  for (int x = t; x < 5 * 256; x += NTHR) (&clsW[51][0])[x] = ecW0[x];
  for (int x = t; x < 4 * 256; x += NTHR) (&clsW[56][0])[x] = ecW1[x];
  if (t < 40) clsB[t] = ncb0[t];
  else if (t < 46) clsB[t] = ncb1[t - 40];
  else if (t < 51) clsB[t] = ncb2[t - 46];
  else if (t < 56) clsB[t] = ecb0[t - 51];
  else if (t < 60) clsB[t] = ecb1[t - 56];

  const float nbih0 = nbih[tc], nbih1 = nbih[256 + tc], nbih2 = nbih[512 + tc];
  const float nbhh0 = nbhh[tc], nbhh1 = nbhh[256 + tc], nbhh2 = nbhh[512 + tc];
  const float ebih0 = ebih[tc], ebih1 = ebih[256 + tc], ebih2 = ebih[512 + tc];
  const float ebhh0 = ebhh[tc], ebhh1 = ebhh[256 + tc], ebhh2 = ebhh[512 + tc];

  if (isg) {
#pragma unroll
    for (int r = 0; r < NR; ++r) {
      hs[0][r][tc] = 0.f;
      ht[r][tc] = h0[(size_t)(b0 + r) * 256 + tc];
    }
  }
  if (t < NR) nnL[t] = -1.f;
  __syncthreads();

  int hp = 0;                        // hs[hp] holds current valid edge_h
  for (int i = 0; i < 50; ++i) {
    const int cur = i & 1, prv = cur ^ 1;
    const int L = (i < 12) ? i : 12;

    // ---- Phase A: build ht (gemv waves) ----
    if (i >= 1) {
      if (isg) {
#pragma unroll
        for (int r = 0; r < NR; ++r) {
          float v = xb[prv][r][tc];
          if (i >= 2) v += hs[hp][r][tc];
          ht[r][tc] = v;
        }
      }
      __syncthreads();
    }

    // ---- Phase B: node GRU (gemv) || deferred edge-cls(i-1, last) (cls) ----
    if (isg) {
      float gi[3][NR], gh[3][NR];
      if (i >= 1) {
        gemv6(Wih4, Whh4, xb[prv], ht, tc, gi, gh);
      } else {
        gemv3(Whh4, ht, tc, gh);
#pragma unroll
        for (int g = 0; g < 3; ++g)
#pragma unroll
          for (int r = 0; r < NR; ++r) gi[g][r] = 0.f;
      }
#pragma unroll
      for (int r = 0; r < NR; ++r) {
        float ir  = gi[0][r] + nbih0;
        float iz  = gi[1][r] + nbih1;
        float inn = gi[2][r] + nbih2;
        float hr = gh[0][r] + nbhh0;
        float hz = gh[1][r] + nbhh1;
        float hn = gh[2][r] + nbhh2;
        float h = ht[r][tc];
        float rr = 1.f / (1.f + expf(-(ir + hr)));
        float zg = 1.f / (1.f + expf(-(iz + hz)));
        float n = tanhf(inn + rr * hn);
        float hv = (1.f - zg) * n + zg * h;
        xb[cur][r][tc] = hv;
        if (i >= 1) hs[hp ^ 1][r][tc] = hs[hp][r][tc] + hv;  // edge_h += node_h
      }
    } else if (i >= 2) {
      const int Lp = ((i - 1) < 12) ? (i - 1) : 12;
      edge_cls_step(i - 1, Lp - 1, hs[hp], tc, b0, &clsW[0][0], clsB, o_ef,
                    o_el);
    }
    __syncthreads();
    if (i >= 1) hp ^= 1;

    // ---- Phase C: edge scan (gemv) || classifiers + eih (cls) ----
    if (i == 0) {
      if (isg) do_eih(Eih4, xb[cur], tc, egi, 0, ebih0, ebih1, ebih2);
      else node_cls_all(xb[cur], tc, b0, 0, &clsW[0][0], clsB, o_nf, o_nl,
                        nnL);
      __syncthreads();
    } else {
      const int sE = (L >= 2) ? 1 : 0;
      for (int s = 0; s < L; ++s) {
        if (isg) {
          const float* eg = egi + (size_t)((i - 1 - s) % 13) * 1536 + tc * 6;
          float2 f0 = *(const float2*)(eg);
          float2 f1 = *(const float2*)(eg + 2);
          float2 f2 = *(const float2*)(eg + 4);
          float a[3][NR];
          gemv3(Ehh4, hs[hp], tc, a);
          float ir_[NR] = {f0.x, f1.y};
          float iz_[NR] = {f0.y, f2.x};
          float in_[NR] = {f1.x, f2.y};
#pragma unroll
          for (int r = 0; r < NR; ++r) {
            float hr = a[0][r] + ebhh0;
            float hz = a[1][r] + ebhh1;
            float hn = a[2][r] + ebhh2;
            float h = hs[hp][r][tc];
            float rr = 1.f / (1.f + expf(-(ir_[r] + hr)));
            float zg = 1.f / (1.f + expf(-(iz_[r] + hz)));
            float n = tanhf(in_[r] + rr * hn);
            hs[hp ^ 1][r][tc] = (1.f - zg) * n + zg * h;
          }
        } else {
          if (s == 0)
            node_cls_all(xb[cur], tc, b0, i, &clsW[0][0], clsB, o_nf, o_nl,
                         nnL);
          if (s == sE && i <= 48)
            do_eih(Eih4, xb[cur], tc, egi, i % 13, ebih0, ebih1, ebih2);
          if (s >= 1)
            edge_cls_step(i, s - 1, hs[hp], tc, b0, &clsW[0][0], clsB, o_ef,
                          o_el);
        }
        __syncthreads();
        hp ^= 1;
      }
    }
  }

  // ---- final: last edge classifier + num_nodes ----
  if (!isg)
    edge_cls_step(49, 11, hs[hp], tc, b0, &clsW[0][0], clsB, o_ef, o_el);
  if (t < NR) {
    float v = nnL[t];
    __builtin_nontemporal_store((v == -1.f) ? 50.f : v, &out[b0 + t]);
  }
}

// ---------------- host ----------------
extern "C" void kernel_launch(void* const* d_in, const int* in_sizes, int n_in,
                              void* d_out, int out_size, void* d_ws,
                              size_t ws_size, hipStream_t stream) {
  (void)in_sizes; (void)n_in; (void)out_size; (void)ws_size;
  const float* z    = (const float*)d_in[0];
  const float* lpW  = (const float*)d_in[1];
  const float* lpb  = (const float*)d_in[2];
  const float* nWih = (const float*)d_in[3];
  const float* nWhh = (const float*)d_in[4];
  const float* nbih = (const float*)d_in[5];
  const float* nbhh = (const float*)d_in[6];
  const float* eWih = (const float*)d_in[7];
  const float* eWhh = (const float*)d_in[8];
  const float* ebih = (const float*)d_in[9];
  const float* ebhh = (const float*)d_in[10];
  const float* ncW0 = (const float*)d_in[11];
  const float* ncb0 = (const float*)d_in[12];
  const float* ncW1 = (const float*)d_in[13];
  const float* ncb1 = (const float*)d_in[14];
  const float* ncW2 = (const float*)d_in[15];
  const float* ncb2 = (const float*)d_in[16];
  const float* ecW0 = (const float*)d_in[17];
  const float* ecb0 = (const float*)d_in[18];
  const float* ecW1 = (const float*)d_in[19];
  const float* ecb1 = (const float*)d_in[20];

  setup_k<<<dim3(832), dim3(256), 0, stream>>>(nWih, nWhh, eWih, eWhh, z, lpW,
                                               lpb, (float*)d_ws);
  fused_rnn<<<dim3(NWG), dim3(NTHR), 0, stream>>>(
      nbih, nbhh, ebih, ebhh, ncW0, ncb0, ncW1, ncb1, ncW2, ncb2, ecW0, ecb0,
      ecW1, ecb1, (float*)d_ws, (float*)d_out);
}